// Round 3
// baseline (10729.803 us; speedup 1.0000x reference)
//
#include <hip/hip_runtime.h>

// ---------------------------------------------------------------------------
// MyGRU_GAT on MI355X.
// R7: scan restructure — 16 WGs x 512 threads (32 cols/WG). Each 16-lane
//     group owns one output column end-to-end: register weights, shfl
//     reduce, lane-0 finalize+store. No LDS reductions, 3 syncs/step,
//     merged phase B. Same epoch-tagged u64 exchange protocol as R6.
// Pipeline: detect -> prep_att -> transposes -> gat -> gemm_a1 ->
//           persistent scan -> gemm_logits -> logsoftmax fixup.
// ---------------------------------------------------------------------------

typedef unsigned short u16;
typedef unsigned long long u64;
typedef __attribute__((ext_vector_type(8))) short s16x8;
typedef __attribute__((ext_vector_type(8))) u16  u16x8;
typedef __attribute__((ext_vector_type(4))) float f32x4;

__device__ __forceinline__ float bf2f(u16 u) {
    unsigned int x = ((unsigned int)u) << 16;
    return __uint_as_float(x);
}
__device__ __forceinline__ u16 f2bf(float f) {
    unsigned int x = __float_as_uint(f);
    x = x + 0x7fffu + ((x >> 16) & 1u);   // RNE
    return (u16)(x >> 16);
}
__device__ __forceinline__ float sigmoidf_(float x) { return 1.f / (1.f + __expf(-x)); }
// dual-mode input load: m=1 -> fp32, m=0 -> bf16
__device__ __forceinline__ float ldin(const void* p, size_t i, int m) {
    return m ? ((const float*)p)[i] : bf2f(((const u16*)p)[i]);
}
__device__ __forceinline__ bool nanf_(float v) { return !(v == v); }

// tagged-exchange helpers: u64 = {epoch:32 | f32 bits:32}
__device__ __forceinline__ u64 packtag(float v, unsigned int e) {
    return ((u64)e << 32) | (u64)__float_as_uint(v);
}
__device__ __forceinline__ float tagval(u64 x) { return __uint_as_float((unsigned int)x); }
__device__ __forceinline__ unsigned int tagof(u64 x) { return (unsigned int)(x >> 32); }

#define AL64(p) __hip_atomic_load((p), __ATOMIC_RELAXED, __HIP_MEMORY_SCOPE_AGENT)
#define AS64(p, v) __hip_atomic_store((p), (v), __ATOMIC_RELAXED, __HIP_MEMORY_SCOPE_AGENT)

// ---------------- constants ----------------
#define S_SEQ 512      // B*T
#define NND   32       // nodes per subgraph
#define DIM   512
#define NHEAD 8
#define CI    1024
#define NV3   1536
#define VOC   50000
#define KWG   16       // scan workgroups
#define CCOL  32       // columns per scan WG
#define TSTEPS 512

// ---------------- ws offsets (bytes) ----------------
// zero region [0,28672): mode, flags, rowsum, tagged h1/h2/r1/r2
#define OFF_MODE    0
#define OFF_FLAGS   4
#define OFF_ROWSUM  256              // f32[512]
#define OFF_G1      4096             // u64[2][512] tagged h1
#define OFF_G2      12288            // u64[2][512] tagged h2
#define OFF_R1      20480            // u64[512] tagged r1
#define OFF_R2      24576            // u64[512] tagged r2
#define ZERO_BYTES  28672
#define OFF_WAS     28672
#define OFF_WAD     45056
#define OFF_INP     61440            // bf16 [512][1024]
#define OFF_A1      1110016          // f32  [512][1536]
#define OFF_H2      4255744          // bf16 [512][512]
#define OFF_WST     4780032          // bf16 9x[512][512] transposed
#define OFF_WCATT   9498624          // bf16 [1536][1024]
// end = 12644352 bytes (~12.6 MB)

// ---------------------------------------------------------------------------
// detect_mode: fp32 data read as u16 has ~50% of lanes with exponent>=2.0;
// bf16 data at scale 0.02 has none.
// ---------------------------------------------------------------------------
__global__ void detect_mode(const void* X, int* mode) {
    const u16* p = (const u16*)X;
    int tid = threadIdx.x;
    int hits = 0;
    for (int i = tid; i < 1024; i += 64) {
        u16 u = p[i];
        if ((u & 0x7f80u) >= 0x4000u) hits++;
    }
    hits += __shfl_xor(hits, 1);  hits += __shfl_xor(hits, 2);
    hits += __shfl_xor(hits, 4);  hits += __shfl_xor(hits, 8);
    hits += __shfl_xor(hits, 16); hits += __shfl_xor(hits, 32);
    if (tid == 0) *mode = (hits > 8) ? 1 : 0;
}

// ---------------------------------------------------------------------------
// prep_att: WAs[d][h] = sum_k W_gat[d][h*64+k]*att_src[h][k]; same for WAd.
// ---------------------------------------------------------------------------
__global__ void prep_att(const void* __restrict__ Wgat, const void* __restrict__ asrc,
                         const void* __restrict__ adst, float* __restrict__ WAs,
                         float* __restrict__ WAd, const int* __restrict__ modep) {
    const int m = *modep;
    int id = blockIdx.x * 256 + threadIdx.x;      // 0..8191
    int which = id >> 12;
    int rem = id & 4095;
    int d = rem >> 3, h = rem & 7;
    const void* att = which ? adst : asrc;
    float sum = 0.f;
#pragma unroll 8
    for (int k = 0; k < 64; ++k)
        sum += ldin(Wgat, d * 512 + h * 64 + k, m) * ldin(att, h * 64 + k, m);
    (which ? WAd : WAs)[d * 8 + h] = sum;
}

// ---------------------------------------------------------------------------
// transposes -> bf16. tile 32x32, 256 threads.
// ---------------------------------------------------------------------------
struct Ptrs9 { const void* p[9]; };
__global__ void transpose9(Ptrs9 ps, u16* __restrict__ dst, const int* __restrict__ modep) {
    const int m = *modep;
    __shared__ u16 tile[32][33];
    const void* src = ps.p[blockIdx.z];
    u16* d = dst + (size_t)blockIdx.z * 262144;
    int c0 = blockIdx.x * 32, r0 = blockIdx.y * 32;
    int tx = threadIdx.x & 31, ty = threadIdx.x >> 5;
#pragma unroll
    for (int i = 0; i < 32; i += 8)
        tile[ty + i][tx] = f2bf(ldin(src, (size_t)(r0 + ty + i) * 512 + c0 + tx, m));
    __syncthreads();
#pragma unroll
    for (int i = 0; i < 32; i += 8)
        d[(size_t)(c0 + ty + i) * 512 + r0 + tx] = tile[tx][ty + i];
}

struct Ptrs3 { const void* p[3]; };
__global__ void transpose3(Ptrs3 ps, u16* __restrict__ dst, const int* __restrict__ modep) {
    // [1024][512] -> [512][1024]
    const int m = *modep;
    __shared__ u16 tile[32][33];
    const void* src = ps.p[blockIdx.z];
    u16* d = dst + (size_t)blockIdx.z * 524288;
    int c0 = blockIdx.x * 32, r0 = blockIdx.y * 32;
    int tx = threadIdx.x & 31, ty = threadIdx.x >> 5;
#pragma unroll
    for (int i = 0; i < 32; i += 8)
        tile[ty + i][tx] = f2bf(ldin(src, (size_t)(r0 + ty + i) * 512 + c0 + tx, m));
    __syncthreads();
#pragma unroll
    for (int i = 0; i < 32; i += 8)
        d[(size_t)(c0 + ty + i) * 1024 + r0 + tx] = tile[tx][ty + i];
}

// ---------------------------------------------------------------------------
// GAT: one WG per subgraph; only node-0 output is needed.
// ---------------------------------------------------------------------------
__global__ __launch_bounds__(256) void gat_kernel(
    const int* __restrict__ xidx, const int* __restrict__ eidx,
    const void* __restrict__ X, const void* __restrict__ Wgat,
    const float* __restrict__ WAs, const float* __restrict__ WAd,
    const void* __restrict__ bgat, u16* __restrict__ inp,
    const int* __restrict__ modep, int* __restrict__ flags) {
    const int m = *modep;
    int s = blockIdx.x, tid = threadIdx.x;
    __shared__ int idxL[NND];
    __shared__ int srcL[260];
    __shared__ int nsrcL;
    __shared__ float asL[NND][NHEAD];
    __shared__ float ad0[NHEAD];
    __shared__ float scoresL[257 * NHEAD];
    __shared__ float denL[NHEAD];
    __shared__ float xbL[NHEAD][DIM];

    if (tid < NND) idxL[tid] = xidx[s * NND + tid];
    if (tid == 0) nsrcL = 0;
    __syncthreads();

    { // a_s for all nodes; a_d for node 0
        int n = tid >> 3, h = tid & 7;
        size_t xoff = (size_t)idxL[n] * DIM;
        float acc = 0.f, accd = 0.f;
        for (int d = 0; d < DIM; ++d) {
            float xv = ldin(X, xoff + d, m);
            acc  += xv * WAs[d * 8 + h];
            accd += xv * WAd[d * 8 + h];
        }
        asL[n][h] = acc;
        if (n == 0) ad0[h] = accd;
    }
    { // build src list for dst==0 (+ self loop)
        int dstn = eidx[s * 512 + 256 + tid];
        if (dstn == 0) {
            int p = atomicAdd(&nsrcL, 1);
            srcL[p] = eidx[s * 512 + tid];
        }
        if (tid == 0) { int p = atomicAdd(&nsrcL, 1); srcL[p] = 0; }
    }
    __syncthreads();
    int nsrc = nsrcL;

    for (int p = tid; p < nsrc * NHEAD; p += 256) {
        int le = p >> 3, h = p & 7;
        float e = asL[srcL[le]][h] + ad0[h];
        e = (e >= 0.f) ? e : 0.2f * e;           // leaky_relu 0.2
        scoresL[le * 8 + h] = e;
    }
    __syncthreads();
    if (tid < NHEAD) {
        int h = tid;
        float mx = -1e30f;
        for (int le = 0; le < nsrc; ++le) mx = fmaxf(mx, scoresL[le * 8 + h]);
        float den = 0.f;
        for (int le = 0; le < nsrc; ++le) {
            float ex = __expf(scoresL[le * 8 + h] - mx);
            scoresL[le * 8 + h] = ex;
            den += ex;
        }
        denL[h] = den + 1e-16f;
    }
    __syncthreads();
    // xb[h][d] = sum_le alpha(le,h) * X[src_le][d]
    for (int p = tid; p < NHEAD * DIM; p += 256) {
        int d = p & 511, h = p >> 9;
        float acc = 0.f;
        for (int le = 0; le < nsrc; ++le)
            acc += scoresL[le * 8 + h] * ldin(X, (size_t)idxL[srcL[le]] * DIM + d, m);
        xbL[h][d] = acc / denL[h];
    }
    __syncthreads();
    // out0[c] = sum_d xb[c>>6][d]*Wgat[d][c] + b_gat[c]; write inp row
    for (int c = tid; c < DIM; c += 256) {
        int h = c >> 6;
        float acc = 0.f;
        for (int d = 0; d < DIM; ++d)
            acc += xbL[h][d] * ldin(Wgat, d * 512 + c, m);
        acc += ldin(bgat, c, m);
        float xv = ldin(X, (size_t)idxL[0] * DIM + c, m);
        if (nanf_(acc)) { atomicOr(flags, 1); acc = 0.f; }
        if (nanf_(xv))  { atomicOr(flags, 1); xv  = 0.f; }
        inp[(size_t)s * CI + DIM + c] = f2bf(acc);
        inp[(size_t)s * CI + c] = f2bf(xv);
    }
}

// ---------------------------------------------------------------------------
// MFMA GEMM #1: A1 = inp @ [Wz1|Wr1|W1] (+ bW1+bU1 on W1 part). fp32 out.
// ---------------------------------------------------------------------------
__global__ __launch_bounds__(256) void gemm_a1(
    const u16* __restrict__ A, const u16* __restrict__ BT,
    const void* __restrict__ bW1, const void* __restrict__ bU1,
    float* __restrict__ C, const int* __restrict__ modep, int* __restrict__ flags) {
    const int m = *modep;
    const int K = CI;
    int tid = threadIdx.x, wave = tid >> 6, lane = tid & 63;
    int mw = wave & 1, nw = wave >> 1, l15 = lane & 15, q = lane >> 4;
    int mbase = blockIdx.y * 64 + mw * 32;
    int nbase = blockIdx.x * 128 + nw * 64;
    f32x4 acc[2][4];
#pragma unroll
    for (int mi = 0; mi < 2; ++mi)
#pragma unroll
        for (int ni = 0; ni < 4; ++ni) acc[mi][ni] = (f32x4){0.f, 0.f, 0.f, 0.f};
    for (int k0 = 0; k0 < K; k0 += 32) {
        s16x8 a[2], b[4];
#pragma unroll
        for (int mi = 0; mi < 2; ++mi)
            a[mi] = *(const s16x8*)(A + (size_t)(mbase + mi * 16 + l15) * K + k0 + q * 8);
#pragma unroll
        for (int ni = 0; ni < 4; ++ni)
            b[ni] = *(const s16x8*)(BT + (size_t)(nbase + ni * 16 + l15) * K + k0 + q * 8);
#pragma unroll
        for (int mi = 0; mi < 2; ++mi)
#pragma unroll
            for (int ni = 0; ni < 4; ++ni)
                acc[mi][ni] = __builtin_amdgcn_mfma_f32_16x16x32_bf16(a[mi], b[ni], acc[mi][ni], 0, 0, 0);
    }
#pragma unroll
    for (int mi = 0; mi < 2; ++mi)
#pragma unroll
        for (int r = 0; r < 4; ++r) {
            int row = mbase + mi * 16 + q * 4 + r;
#pragma unroll
            for (int ni = 0; ni < 4; ++ni) {
                int col = nbase + ni * 16 + l15;
                float v = acc[mi][ni][r];
                if (col >= 1024) v += ldin(bW1, col - 1024, m) + ldin(bU1, col - 1024, m);
                if (nanf_(v)) { atomicOr(flags, 2); v = 0.f; }
                C[(size_t)row * NV3 + col] = v;
            }
        }
}

// ---------------------------------------------------------------------------
// Persistent GRU scan. R7: 16 WGs x 512 threads; 32 cols/WG.
// Thread (jj = tid>>4, g = tid&15): column j = wg*32+jj, k-chunk [32g,32g+32).
// All 9 weight slices in registers. shfl_xor reduce within 16-lane group;
// lane g==0 finalizes gates/updates and stores tagged u64s.
// Tag protocol (same as R6):
//   h1x[t&1]    : tag t    (stored end of round t-1, consumed round t)
//   h2x[(t+1)&1]: tag t (t>=2; else 0 from memset) — holds h2(t-2)
//   r1x/r2x     : tag t    (stored phase A of round t, consumed phase B)
// ---------------------------------------------------------------------------
__global__ __launch_bounds__(512) void scan_kernel(
    const float* __restrict__ A1, const u16* __restrict__ wsT,
    const void* __restrict__ bW2, const void* __restrict__ bU2,
    u64* __restrict__ h1x, u64* __restrict__ h2x,
    u64* __restrict__ r1x, u64* __restrict__ r2x,
    u16* __restrict__ H2,
    const int* __restrict__ modep, int* __restrict__ flags) {
    const int m_ = *modep;
    const int wg = blockIdx.x;
    const int tid = threadIdx.x;
    const int jj = tid >> 4;       // 0..31 owned column
    const int g  = tid & 15;       // k-chunk selector (32 k's each)
    const int j  = wg * CCOL + jj;

    __shared__ float h1c[512], h2c[512], r1c[512], r2c[512];

    // weight slices -> registers.
    // wreg order: 0 Uz1(x1) 1 Ur1(x1) 2 Wz2(x1) 3 Wr2(x1) 4 W2(x1) 5 Uz2(x2) 6 Ur2(x2)
    u16x8 wreg[7][4], u1reg[4], u2reg[4];
#pragma unroll
    for (int m = 0; m < 7; ++m) {
        const u16* src = wsT + (size_t)m * 262144 + (size_t)j * 512 + g * 32;
#pragma unroll
        for (int q = 0; q < 4; ++q) wreg[m][q] = ((const u16x8*)src)[q];
    }
    {
        const u16* s1 = wsT + (size_t)7 * 262144 + (size_t)j * 512 + g * 32;
        const u16* s2 = wsT + (size_t)8 * 262144 + (size_t)j * 512 + g * 32;
#pragma unroll
        for (int q = 0; q < 4; ++q) {
            u1reg[q] = ((const u16x8*)s1)[q];
            u2reg[q] = ((const u16x8*)s2)[q];
        }
    }
    const float bsum = (g == 0) ? ldin(bW2, j, m_) + ldin(bU2, j, m_) : 0.f;

    for (int t = 0; t <= TSTEPS; ++t) {
        const bool need1 = (t < TSTEPS), need2 = (t >= 1);
        // A1 prefetch (independent of exchange)
        float azv = 0.f, arv = 0.f, awk = 0.f;
        if (g == 0 && need1) {
            const float* a1p = A1 + (size_t)t * NV3 + j;
            azv = a1p[0]; arv = a1p[512]; awk = a1p[1024];
        }
        // ---- poll A: h1(t) and h2(t-2) ----
        {
            const unsigned int eg1 = (unsigned int)t;
            const unsigned int eg2 = (t >= 2) ? (unsigned int)t : 0u;
            u64* p1 = h1x + (size_t)(t & 1) * 512 + tid;
            u64* p2 = h2x + (size_t)((t + 1) & 1) * 512 + tid;
            u64 a, b;
            for (;;) {
                a = AL64(p1); b = AL64(p2);
                if (tagof(a) == eg1 && tagof(b) == eg2) break;
                __builtin_amdgcn_s_sleep(1);
            }
            h1c[tid] = tagval(a);
            h2c[tid] = tagval(b);
        }
        __syncthreads();
        // ---- phase A: 7 matvec partials over owned k-chunk ----
        float p0 = 0.f, p1 = 0.f, p2 = 0.f, p3 = 0.f, p4 = 0.f, p5 = 0.f, p6 = 0.f;
#pragma unroll
        for (int q = 0; q < 4; ++q) {
#pragma unroll
            for (int u = 0; u < 8; ++u) {
                const int k = g * 32 + q * 8 + u;
                const float x1 = h1c[k], x2 = h2c[k];
                p0 = fmaf(x1, bf2f(wreg[0][q][u]), p0);
                p1 = fmaf(x1, bf2f(wreg[1][q][u]), p1);
                p2 = fmaf(x1, bf2f(wreg[2][q][u]), p2);
                p3 = fmaf(x1, bf2f(wreg[3][q][u]), p3);
                p4 = fmaf(x1, bf2f(wreg[4][q][u]), p4);
                p5 = fmaf(x2, bf2f(wreg[5][q][u]), p5);
                p6 = fmaf(x2, bf2f(wreg[6][q][u]), p6);
            }
        }
        p0 += __shfl_xor(p0, 1); p0 += __shfl_xor(p0, 2); p0 += __shfl_xor(p0, 4); p0 += __shfl_xor(p0, 8);
        p1 += __shfl_xor(p1, 1); p1 += __shfl_xor(p1, 2); p1 += __shfl_xor(p1, 4); p1 += __shfl_xor(p1, 8);
        p2 += __shfl_xor(p2, 1); p2 += __shfl_xor(p2, 2); p2 += __shfl_xor(p2, 4); p2 += __shfl_xor(p2, 8);
        p3 += __shfl_xor(p3, 1); p3 += __shfl_xor(p3, 2); p3 += __shfl_xor(p3, 4); p3 += __shfl_xor(p3, 8);
        p4 += __shfl_xor(p4, 1); p4 += __shfl_xor(p4, 2); p4 += __shfl_xor(p4, 4); p4 += __shfl_xor(p4, 8);
        p5 += __shfl_xor(p5, 1); p5 += __shfl_xor(p5, 2); p5 += __shfl_xor(p5, 4); p5 += __shfl_xor(p5, 8);
        p6 += __shfl_xor(p6, 1); p6 += __shfl_xor(p6, 2); p6 += __shfl_xor(p6, 4); p6 += __shfl_xor(p6, 8);
        float z1v = 0.f, z2v = 0.f, pw2v = 0.f;
        if (g == 0) {
            if (need1) {
                z1v = sigmoidf_(azv + p0);
                AS64(&r1x[j], packtag(sigmoidf_(arv + p1), (unsigned int)t));
            }
            if (need2) {
                z2v = sigmoidf_(p2 + p5);
                AS64(&r2x[j], packtag(sigmoidf_(p3 + p6), (unsigned int)t));
                pw2v = p4;
            }
        }
        // ---- poll B: r1(t), r2(t) ----
        {
            u64 a = 0, b = 0;
            u64* q1 = r1x + tid;
            u64* q2 = r2x + tid;
            for (;;) {
                if (need1) a = AL64(q1);
                if (need2) b = AL64(q2);
                bool ok = true;
                if (need1) ok = ok && (tagof(a) == (unsigned int)t);
                if (need2) ok = ok && (tagof(b) == (unsigned int)t);
                if (ok) break;
                __builtin_amdgcn_s_sleep(1);
            }
            if (need1) r1c[tid] = tagval(a);
            if (need2) r2c[tid] = tagval(b);
        }
        __syncthreads();
        // ---- phase B: U1 & U2 matvecs merged, update, store ----
        float pa = 0.f, pb = 0.f;
#pragma unroll
        for (int q = 0; q < 4; ++q) {
#pragma unroll
            for (int u = 0; u < 8; ++u) {
                const int k = g * 32 + q * 8 + u;
                pa = fmaf(r1c[k] * h1c[k], bf2f(u1reg[q][u]), pa);
                pb = fmaf(r2c[k] * h2c[k], bf2f(u2reg[q][u]), pb);
            }
        }
        pa += __shfl_xor(pa, 1); pa += __shfl_xor(pa, 2); pa += __shfl_xor(pa, 4); pa += __shfl_xor(pa, 8);
        pb += __shfl_xor(pb, 1); pb += __shfl_xor(pb, 2); pb += __shfl_xor(pb, 4); pb += __shfl_xor(pb, 8);
        if (g == 0) {
            if (need1) {
                float ht1 = tanhf(awk + pa);
                float g1n = z1v * ht1 + (1.f - z1v) * h1c[j];
                if (nanf_(g1n)) { atomicOr(flags, 4); g1n = 0.f; }
                AS64(&h1x[(size_t)((t + 1) & 1) * 512 + j], packtag(g1n, (unsigned int)(t + 1)));
            }
            if (need2) {
                float ht2 = tanhf(pw2v + bsum + pb);
                float g2n = z2v * ht2 + (1.f - z2v) * h2c[j];
                if (nanf_(g2n)) { atomicOr(flags, 4); g2n = 0.f; }
                AS64(&h2x[(size_t)(t & 1) * 512 + j], packtag(g2n, (unsigned int)(t + 1)));
                H2[(size_t)(t - 1) * 512 + j] = f2bf(g2n);
            }
        }
        __syncthreads();   // protect h1c/h2c/r1c/r2c against next round's writes
    }
}

// ---------------------------------------------------------------------------
// MFMA GEMM #2: logits = H2 @ Wg + bg -> d_out (mode dtype), + row exp-sums.
// ---------------------------------------------------------------------------
__global__ __launch_bounds__(256) void gemm_logits(
    const u16* __restrict__ H2, const void* __restrict__ Wg,
    const void* __restrict__ bg, void* __restrict__ out,
    float* __restrict__ rowsum, const int* __restrict__ modep, int* __restrict__ flags) {
    const int m = *modep;
    const int K = DIM;
    int tid = threadIdx.x, wave = tid >> 6, lane = tid & 63;
    int mw = wave & 1, nw = wave >> 1, l15 = lane & 15, q = lane >> 4;
    int mbase = blockIdx.y * 64 + mw * 32;
    int nbase = blockIdx.x * 128 + nw * 64;
    f32x4 acc[2][4];
#pragma unroll
    for (int mi = 0; mi < 2; ++mi)
#pragma unroll
        for (int ni = 0; ni < 4; ++ni) acc[mi][ni] = (f32x4){0.f, 0.f, 0.f, 0.f};
    for (int k0 = 0; k0 < K; k0 += 32) {
        s16x8 a[2], b[4];
#pragma unroll
        for (int mi = 0; mi < 2; ++mi)
            a[mi] = *(const s16x8*)(H2 + (size_t)(mbase + mi * 16 + l15) * K + k0 + q * 8);
#pragma unroll
        for (int ni = 0; ni < 4; ++ni) {
            int n = nbase + ni * 16 + l15;
            if (n >= VOC) n = VOC - 1;
            size_t kb = (size_t)(k0 + q * 8) * VOC + n;
#pragma unroll
            for (int j = 0; j < 8; ++j) b[ni][j] = (short)f2bf(ldin(Wg, kb + (size_t)j * VOC, m));
        }
#pragma unroll
        for (int mi = 0; mi < 2; ++mi)
#pragma unroll
            for (int ni = 0; ni < 4; ++ni)
                acc[mi][ni] = __builtin_amdgcn_mfma_f32_16x16x32_bf16(a[mi], b[ni], acc[mi][ni], 0, 0, 0);
    }
    __shared__ float lds_rows[64];
    if (tid < 64) lds_rows[tid] = 0.f;
    __syncthreads();
#pragma unroll
    for (int mi = 0; mi < 2; ++mi)
#pragma unroll
        for (int r = 0; r < 4; ++r) {
            int row = mbase + mi * 16 + q * 4 + r;
            float esum = 0.f;
#pragma unroll
            for (int ni = 0; ni < 4; ++ni) {
                int col = nbase + ni * 16 + l15;
                float v = acc[mi][ni][r];
                if (col < VOC) {
                    v += ldin(bg, col, m);
                    if (nanf_(v)) { atomicOr(flags, 8); v = 0.f; }
                    if (m) ((float*)out)[(size_t)row * VOC + col] = v;
                    else   ((u16*)out)[(size_t)row * VOC + col] = f2bf(v);
                    esum += __expf(v);
                }
            }
            esum += __shfl_xor(esum, 1); esum += __shfl_xor(esum, 2);
            esum += __shfl_xor(esum, 4); esum += __shfl_xor(esum, 8);
            if (l15 == 0) atomicAdd(&lds_rows[row - blockIdx.y * 64], esum);
        }
    __syncthreads();
    if (tid < 64) atomicAdd(&rowsum[blockIdx.y * 64 + tid], lds_rows[tid]);
}

// ---------------------------------------------------------------------------
// in-place: out = logit - log(rowsum[row]); out[0] += 1000*stage if NaN seen.
// ---------------------------------------------------------------------------
__global__ __launch_bounds__(256) void logsoftmax_fix(void* __restrict__ out,
                                                      const float* __restrict__ rowsum,
                                                      const int* __restrict__ modep,
                                                      int* __restrict__ flags) {
    const int m = *modep;
    int row = blockIdx.y;
    int c0 = blockIdx.x * 2048 + threadIdx.x * 8;
    if (c0 >= VOC) return;
    float rs = rowsum[row];
    float ls = logf(rs);
    if (nanf_(ls) || !(rs > 0.f)) { atomicOr(flags, 16); ls = 0.f; }
    float sentinel = 0.f;
    if (row == 0 && c0 == 0) {
        int f = *flags;
        if (f) sentinel = 1000.f * (float)__ffs(f);
    }
    size_t base = (size_t)row * VOC + c0;
    if (m) {
        float* o = (float*)out;
        int lim = (c0 + 8 <= VOC) ? 8 : (VOC - c0);
        for (int i = 0; i < lim; ++i) {
            float v = o[base + i] - ls;
            if (i == 0) v += sentinel;
            o[base + i] = v;
        }
    } else {
        u16* o = (u16*)out;
        int lim = (c0 + 8 <= VOC) ? 8 : (VOC - c0);
        for (int i = 0; i < lim; ++i) {
            float v = bf2f(o[base + i]) - ls;
            if (i == 0) v += sentinel;
            o[base + i] = f2bf(v);
        }
    }
}

// ---------------------------------------------------------------------------
extern "C" void kernel_launch(void* const* d_in, const int* in_sizes, int n_in,
                              void* d_out, int out_size, void* d_ws, size_t ws_size,
                              hipStream_t stream) {
    const int* xidx = (const int*)d_in[0];
    const int* eidx = (const int*)d_in[1];
    const void* X    = d_in[2];
    const void* Wgat = d_in[3];
    const void* asrc = d_in[4];
    const void* adst = d_in[5];
    const void* bgat = d_in[6];
    const void* Wz1  = d_in[7];
    const void* Uz1  = d_in[8];
    const void* Wr1  = d_in[9];
    const void* Ur1  = d_in[10];
    const void* W1   = d_in[11];
    const void* bW1  = d_in[12];
    const void* U1   = d_in[13];
    const void* bU1  = d_in[14];
    const void* Wz2  = d_in[15];
    const void* Uz2  = d_in[16];
    const void* Wr2  = d_in[17];
    const void* Ur2  = d_in[18];
    const void* W2   = d_in[19];
    const void* bW2  = d_in[20];
    const void* U2   = d_in[21];
    const void* bU2  = d_in[22];
    const void* Wg   = d_in[23];
    const void* bg   = d_in[24];

    char* ws = (char*)d_ws;
    int*   modep  = (int*)(ws + OFF_MODE);
    int*   flags  = (int*)(ws + OFF_FLAGS);
    float* rowsum = (float*)(ws + OFF_ROWSUM);
    u64*   h1x    = (u64*)(ws + OFF_G1);
    u64*   h2x    = (u64*)(ws + OFF_G2);
    u64*   r1x    = (u64*)(ws + OFF_R1);
    u64*   r2x    = (u64*)(ws + OFF_R2);
    float* WAs    = (float*)(ws + OFF_WAS);
    float* WAd    = (float*)(ws + OFF_WAD);
    u16*   inp    = (u16*)(ws + OFF_INP);
    float* A1     = (float*)(ws + OFF_A1);
    u16*   H2     = (u16*)(ws + OFF_H2);
    u16*   wsT    = (u16*)(ws + OFF_WST);
    u16*   WcatT  = (u16*)(ws + OFF_WCATT);

    hipMemsetAsync(ws, 0, ZERO_BYTES, stream);

    detect_mode<<<1, 64, 0, stream>>>(X, modep);

    prep_att<<<32, 256, 0, stream>>>(Wgat, asrc, adst, WAs, WAd, modep);

    Ptrs9 p9; // order: Uz1,Ur1,Wz2,Wr2,W2,Uz2,Ur2,U1,U2
    p9.p[0] = Uz1; p9.p[1] = Ur1; p9.p[2] = Wz2; p9.p[3] = Wr2; p9.p[4] = W2;
    p9.p[5] = Uz2; p9.p[6] = Ur2; p9.p[7] = U1;  p9.p[8] = U2;
    transpose9<<<dim3(16, 16, 9), 256, 0, stream>>>(p9, wsT, modep);

    Ptrs3 p3; p3.p[0] = Wz1; p3.p[1] = Wr1; p3.p[2] = W1;
    transpose3<<<dim3(16, 32, 3), 256, 0, stream>>>(p3, WcatT, modep);

    gat_kernel<<<S_SEQ, 256, 0, stream>>>(xidx, eidx, X, Wgat, WAs, WAd, bgat, inp, modep, flags);

    gemm_a1<<<dim3(NV3 / 128, S_SEQ / 64), 256, 0, stream>>>(inp, WcatT, bW1, bU1, A1, modep, flags);

    scan_kernel<<<KWG, 512, 0, stream>>>(A1, wsT, bW2, bU2, h1x, h2x, r1x, r2x, H2, modep, flags);

    gemm_logits<<<dim3((VOC + 127) / 128, S_SEQ / 64), 256, 0, stream>>>(H2, Wg, bg, d_out, rowsum, modep, flags);

    logsoftmax_fix<<<dim3(25, S_SEQ), 256, 0, stream>>>(d_out, rowsum, modep, flags);
}

// Round 5
// 2609.391 us; speedup vs baseline: 4.1120x; 4.1120x over previous
//
#include <hip/hip_runtime.h>

// ---------------------------------------------------------------------------
// MyGRU_GAT on MI355X.
// R9 (= R8 with compile fix): scan in R6 frame (64WGx256, stride-16 chunks).
//     Step reorg: r-critical matvecs first -> early r-store; z/W matvecs
//     overlap the r-round; merged phase B; 5 syncs/step.
//     Wg pre-transposed to bf16 [n][k] (ws_size-guarded) so gemm_logits
//     loads B coalesced instead of column-strided scalar.
// ---------------------------------------------------------------------------

typedef unsigned short u16;
typedef unsigned long long u64;
typedef __attribute__((ext_vector_type(8))) short s16x8;
typedef __attribute__((ext_vector_type(8))) u16  u16x8;
typedef __attribute__((ext_vector_type(4))) float f32x4;

__device__ __forceinline__ float bf2f(u16 u) {
    unsigned int x = ((unsigned int)u) << 16;
    return __uint_as_float(x);
}
__device__ __forceinline__ u16 f2bf(float f) {
    unsigned int x = __float_as_uint(f);
    x = x + 0x7fffu + ((x >> 16) & 1u);   // RNE
    return (u16)(x >> 16);
}
__device__ __forceinline__ float sigmoidf_(float x) { return 1.f / (1.f + __expf(-x)); }
// dual-mode input load: m=1 -> fp32, m=0 -> bf16
__device__ __forceinline__ float ldin(const void* p, size_t i, int m) {
    return m ? ((const float*)p)[i] : bf2f(((const u16*)p)[i]);
}
__device__ __forceinline__ bool nanf_(float v) { return !(v == v); }

// tagged-exchange helpers: u64 = {epoch:32 | f32 bits:32}
__device__ __forceinline__ u64 packtag(float v, unsigned int e) {
    return ((u64)e << 32) | (u64)__float_as_uint(v);
}
__device__ __forceinline__ float tagval(u64 x) { return __uint_as_float((unsigned int)x); }
__device__ __forceinline__ unsigned int tagof(u64 x) { return (unsigned int)(x >> 32); }

#define AL64(p) __hip_atomic_load((p), __ATOMIC_RELAXED, __HIP_MEMORY_SCOPE_AGENT)
#define AS64(p, v) __hip_atomic_store((p), (v), __ATOMIC_RELAXED, __HIP_MEMORY_SCOPE_AGENT)

// ---------------- constants ----------------
#define S_SEQ 512      // B*T
#define NND   32       // nodes per subgraph
#define DIM   512
#define NHEAD 8
#define CI    1024
#define NV3   1536
#define VOC   50000
#define KWG   64       // scan workgroups
#define TSTEPS 512

// ---------------- ws offsets (bytes) ----------------
// zero region [0,28672): mode, flags, rowsum, tagged h1/h2/r1/r2
#define OFF_MODE    0
#define OFF_FLAGS   4
#define OFF_ROWSUM  256              // f32[512]
#define OFF_G1      4096             // u64[2][512] tagged h1
#define OFF_G2      12288            // u64[2][512] tagged h2
#define OFF_R1      20480            // u64[512] tagged r1
#define OFF_R2      24576            // u64[512] tagged r2
#define ZERO_BYTES  28672
#define OFF_WAS     28672
#define OFF_WAD     45056
#define OFF_INP     61440            // bf16 [512][1024]
#define OFF_A1      1110016          // f32  [512][1536]
#define OFF_H2      4255744          // bf16 [512][512]
#define OFF_WST     4780032          // bf16 9x[512][512] transposed
#define OFF_WCATT   9498624          // bf16 [1536][1024]
#define OFF_WGT     12644352         // bf16 [50048][512] Wg transposed (optional)
#define WGT_BYTES   (50048ull * 512ull * 2ull)
#define WS_NEED_BIG (12644352ull + WGT_BYTES)

// ---------------------------------------------------------------------------
__global__ void detect_mode(const void* X, int* mode) {
    const u16* p = (const u16*)X;
    int tid = threadIdx.x;
    int hits = 0;
    for (int i = tid; i < 1024; i += 64) {
        u16 u = p[i];
        if ((u & 0x7f80u) >= 0x4000u) hits++;
    }
    hits += __shfl_xor(hits, 1);  hits += __shfl_xor(hits, 2);
    hits += __shfl_xor(hits, 4);  hits += __shfl_xor(hits, 8);
    hits += __shfl_xor(hits, 16); hits += __shfl_xor(hits, 32);
    if (tid == 0) *mode = (hits > 8) ? 1 : 0;
}

// ---------------------------------------------------------------------------
// prep_att: WAs[d][h] = sum_k W_gat[d][h*64+k]*att_src[h][k]; same for WAd.
// ---------------------------------------------------------------------------
__global__ void prep_att(const void* __restrict__ Wgat, const void* __restrict__ asrc,
                         const void* __restrict__ adst, float* __restrict__ WAs,
                         float* __restrict__ WAd, const int* __restrict__ modep) {
    const int m = *modep;
    int id = blockIdx.x * 256 + threadIdx.x;      // 0..8191
    int which = id >> 12;
    int rem = id & 4095;
    int d = rem >> 3, h = rem & 7;
    const void* att = which ? adst : asrc;
    float sum = 0.f;
#pragma unroll 8
    for (int k = 0; k < 64; ++k)
        sum += ldin(Wgat, d * 512 + h * 64 + k, m) * ldin(att, h * 64 + k, m);
    (which ? WAd : WAs)[d * 8 + h] = sum;
}

// ---------------------------------------------------------------------------
// transposes -> bf16. tile 32x32, 256 threads.
// ---------------------------------------------------------------------------
struct Ptrs9 { const void* p[9]; };
__global__ void transpose9(Ptrs9 ps, u16* __restrict__ dst, const int* __restrict__ modep) {
    const int m = *modep;
    __shared__ u16 tile[32][33];
    const void* src = ps.p[blockIdx.z];
    u16* d = dst + (size_t)blockIdx.z * 262144;
    int c0 = blockIdx.x * 32, r0 = blockIdx.y * 32;
    int tx = threadIdx.x & 31, ty = threadIdx.x >> 5;
#pragma unroll
    for (int i = 0; i < 32; i += 8)
        tile[ty + i][tx] = f2bf(ldin(src, (size_t)(r0 + ty + i) * 512 + c0 + tx, m));
    __syncthreads();
#pragma unroll
    for (int i = 0; i < 32; i += 8)
        d[(size_t)(c0 + ty + i) * 512 + r0 + tx] = tile[tx][ty + i];
}

struct Ptrs3 { const void* p[3]; };
__global__ void transpose3(Ptrs3 ps, u16* __restrict__ dst, const int* __restrict__ modep) {
    // [1024][512] -> [512][1024]
    const int m = *modep;
    __shared__ u16 tile[32][33];
    const void* src = ps.p[blockIdx.z];
    u16* d = dst + (size_t)blockIdx.z * 524288;
    int c0 = blockIdx.x * 32, r0 = blockIdx.y * 32;
    int tx = threadIdx.x & 31, ty = threadIdx.x >> 5;
#pragma unroll
    for (int i = 0; i < 32; i += 8)
        tile[ty + i][tx] = f2bf(ldin(src, (size_t)(r0 + ty + i) * 512 + c0 + tx, m));
    __syncthreads();
#pragma unroll
    for (int i = 0; i < 32; i += 8)
        d[(size_t)(c0 + ty + i) * 1024 + r0 + tx] = tile[tx][ty + i];
}

// Wg [512][50000] -> WgT bf16 [n][k] ([50048][512], rows >= VOC untouched)
__global__ void transpose_wg(const void* __restrict__ Wg, u16* __restrict__ dst,
                             const int* __restrict__ modep) {
    const int m = *modep;
    __shared__ u16 tile[32][33];
    int c0 = blockIdx.x * 32;   // n base
    int r0 = blockIdx.y * 32;   // k base
    int tx = threadIdx.x & 31, ty = threadIdx.x >> 5;
#pragma unroll
    for (int i = 0; i < 32; i += 8) {
        int n = c0 + tx;
        tile[ty + i][tx] = (n < VOC)
            ? f2bf(ldin(Wg, (size_t)(r0 + ty + i) * VOC + n, m)) : (u16)0;
    }
    __syncthreads();
#pragma unroll
    for (int i = 0; i < 32; i += 8) {
        int n = c0 + ty + i;
        if (n < VOC) dst[(size_t)n * 512 + r0 + tx] = tile[tx][ty + i];
    }
}

// ---------------------------------------------------------------------------
// GAT: one WG per subgraph; only node-0 output is needed.
// ---------------------------------------------------------------------------
__global__ __launch_bounds__(256) void gat_kernel(
    const int* __restrict__ xidx, const int* __restrict__ eidx,
    const void* __restrict__ X, const void* __restrict__ Wgat,
    const float* __restrict__ WAs, const float* __restrict__ WAd,
    const void* __restrict__ bgat, u16* __restrict__ inp,
    const int* __restrict__ modep, int* __restrict__ flags) {
    const int m = *modep;
    int s = blockIdx.x, tid = threadIdx.x;
    __shared__ int idxL[NND];
    __shared__ int srcL[260];
    __shared__ int nsrcL;
    __shared__ float asL[NND][NHEAD];
    __shared__ float ad0[NHEAD];
    __shared__ float scoresL[257 * NHEAD];
    __shared__ float denL[NHEAD];
    __shared__ float xbL[NHEAD][DIM];

    if (tid < NND) idxL[tid] = xidx[s * NND + tid];
    if (tid == 0) nsrcL = 0;
    __syncthreads();

    { // a_s for all nodes; a_d for node 0
        int n = tid >> 3, h = tid & 7;
        size_t xoff = (size_t)idxL[n] * DIM;
        float acc = 0.f, accd = 0.f;
        for (int d = 0; d < DIM; ++d) {
            float xv = ldin(X, xoff + d, m);
            acc  += xv * WAs[d * 8 + h];
            accd += xv * WAd[d * 8 + h];
        }
        asL[n][h] = acc;
        if (n == 0) ad0[h] = accd;
    }
    { // build src list for dst==0 (+ self loop)
        int dstn = eidx[s * 512 + 256 + tid];
        if (dstn == 0) {
            int p = atomicAdd(&nsrcL, 1);
            srcL[p] = eidx[s * 512 + tid];
        }
        if (tid == 0) { int p = atomicAdd(&nsrcL, 1); srcL[p] = 0; }
    }
    __syncthreads();
    int nsrc = nsrcL;

    for (int p = tid; p < nsrc * NHEAD; p += 256) {
        int le = p >> 3, h = p & 7;
        float e = asL[srcL[le]][h] + ad0[h];
        e = (e >= 0.f) ? e : 0.2f * e;           // leaky_relu 0.2
        scoresL[le * 8 + h] = e;
    }
    __syncthreads();
    if (tid < NHEAD) {
        int h = tid;
        float mx = -1e30f;
        for (int le = 0; le < nsrc; ++le) mx = fmaxf(mx, scoresL[le * 8 + h]);
        float den = 0.f;
        for (int le = 0; le < nsrc; ++le) {
            float ex = __expf(scoresL[le * 8 + h] - mx);
            scoresL[le * 8 + h] = ex;
            den += ex;
        }
        denL[h] = den + 1e-16f;
    }
    __syncthreads();
    // xb[h][d] = sum_le alpha(le,h) * X[src_le][d]
    for (int p = tid; p < NHEAD * DIM; p += 256) {
        int d = p & 511, h = p >> 9;
        float acc = 0.f;
        for (int le = 0; le < nsrc; ++le)
            acc += scoresL[le * 8 + h] * ldin(X, (size_t)idxL[srcL[le]] * DIM + d, m);
        xbL[h][d] = acc / denL[h];
    }
    __syncthreads();
    // out0[c] = sum_d xb[c>>6][d]*Wgat[d][c] + b_gat[c]; write inp row
    for (int c = tid; c < DIM; c += 256) {
        int h = c >> 6;
        float acc = 0.f;
        for (int d = 0; d < DIM; ++d)
            acc += xbL[h][d] * ldin(Wgat, d * 512 + c, m);
        acc += ldin(bgat, c, m);
        float xv = ldin(X, (size_t)idxL[0] * DIM + c, m);
        if (nanf_(acc)) { atomicOr(flags, 1); acc = 0.f; }
        if (nanf_(xv))  { atomicOr(flags, 1); xv  = 0.f; }
        inp[(size_t)s * CI + DIM + c] = f2bf(acc);
        inp[(size_t)s * CI + c] = f2bf(xv);
    }
}

// ---------------------------------------------------------------------------
// MFMA GEMM #1: A1 = inp @ [Wz1|Wr1|W1] (+ bW1+bU1 on W1 part). fp32 out.
// ---------------------------------------------------------------------------
__global__ __launch_bounds__(256) void gemm_a1(
    const u16* __restrict__ A, const u16* __restrict__ BT,
    const void* __restrict__ bW1, const void* __restrict__ bU1,
    float* __restrict__ C, const int* __restrict__ modep, int* __restrict__ flags) {
    const int m = *modep;
    const int K = CI;
    int tid = threadIdx.x, wave = tid >> 6, lane = tid & 63;
    int mw = wave & 1, nw = wave >> 1, l15 = lane & 15, q = lane >> 4;
    int mbase = blockIdx.y * 64 + mw * 32;
    int nbase = blockIdx.x * 128 + nw * 64;
    f32x4 acc[2][4];
#pragma unroll
    for (int mi = 0; mi < 2; ++mi)
#pragma unroll
        for (int ni = 0; ni < 4; ++ni) acc[mi][ni] = (f32x4){0.f, 0.f, 0.f, 0.f};
    for (int k0 = 0; k0 < K; k0 += 32) {
        s16x8 a[2], b[4];
#pragma unroll
        for (int mi = 0; mi < 2; ++mi)
            a[mi] = *(const s16x8*)(A + (size_t)(mbase + mi * 16 + l15) * K + k0 + q * 8);
#pragma unroll
        for (int ni = 0; ni < 4; ++ni)
            b[ni] = *(const s16x8*)(BT + (size_t)(nbase + ni * 16 + l15) * K + k0 + q * 8);
#pragma unroll
        for (int mi = 0; mi < 2; ++mi)
#pragma unroll
            for (int ni = 0; ni < 4; ++ni)
                acc[mi][ni] = __builtin_amdgcn_mfma_f32_16x16x32_bf16(a[mi], b[ni], acc[mi][ni], 0, 0, 0);
    }
#pragma unroll
    for (int mi = 0; mi < 2; ++mi)
#pragma unroll
        for (int r = 0; r < 4; ++r) {
            int row = mbase + mi * 16 + q * 4 + r;
#pragma unroll
            for (int ni = 0; ni < 4; ++ni) {
                int col = nbase + ni * 16 + l15;
                float v = acc[mi][ni][r];
                if (col >= 1024) v += ldin(bW1, col - 1024, m) + ldin(bU1, col - 1024, m);
                if (nanf_(v)) { atomicOr(flags, 2); v = 0.f; }
                C[(size_t)row * NV3 + col] = v;
            }
        }
}

// ---------------------------------------------------------------------------
// Persistent GRU scan. R9: 64 WGs x 256 threads (R6 frame), reorganized:
//   poll h -> S1 -> r-matvecs -> S2 -> early r store -> z/W matvecs
//   (overlap r round) -> poll r -> S3 -> merged U1/U2 matvec -> S4 ->
//   finalize both layers + store h' -> S5.
// Tag protocol (identical to R6):
//   h1x[t&1]    : tag t    (stored end of round t-1, consumed round t)
//   h2x[(t+1)&1]: tag t (t>=2; else 0 from memset) — holds h2(t-2)
//   r1x/r2x     : tag t    (stored early in round t, consumed later in t)
// ---------------------------------------------------------------------------
__global__ __launch_bounds__(256) void scan_kernel(
    const float* __restrict__ A1, const u16* __restrict__ wsT,
    const void* __restrict__ bW2, const void* __restrict__ bU2,
    u64* __restrict__ h1x, u64* __restrict__ h2x,
    u64* __restrict__ r1x, u64* __restrict__ r2x,
    u16* __restrict__ H2,
    const int* __restrict__ modep, int* __restrict__ flags) {
    const int m_ = *modep;
    const int wg = blockIdx.x;
    const int tid = threadIdx.x;
    const int jj = tid & 7, g = tid >> 3;     // j = j0+jj, k-chunk [16g,16g+16)
    const int j0 = wg * 8;
    const int lane = tid & 63, wave = tid >> 6;

    __shared__ float h1c[512], h2c[512], r1c[512], r2c[512];
    __shared__ float red[4][7][8];

    // loop-invariant weights -> registers (stride-16 chunks: 2-way bank
    // aliasing on LDS reads = free; R7's stride-32 was 16-way = fatal).
    // wreg order: 0 Uz1(h1) 1 Ur1(h1) 2 Wz2(h1) 3 Wr2(h1) 4 W2(h1) 5 Uz2(h2) 6 Ur2(h2)
    u16x8 wreg[14];
#pragma unroll
    for (int m = 0; m < 7; ++m) {
        const u16* src = wsT + (size_t)m * 262144 + (size_t)(j0 + jj) * 512 + g * 16;
        wreg[2 * m]     = *(const u16x8*)src;
        wreg[2 * m + 1] = *(const u16x8*)(src + 8);
    }
    const u16* u1col = wsT + (size_t)7 * 262144 + (size_t)(j0 + jj) * 512;
    const u16* u2col = wsT + (size_t)8 * 262144 + (size_t)(j0 + jj) * 512;
    const u16x8 u1w0 = *(const u16x8*)(u1col + g * 16);
    const u16x8 u1w1 = *(const u16x8*)(u1col + g * 16 + 8);
    const u16x8 u2w0 = *(const u16x8*)(u2col + g * 16);
    const u16x8 u2w1 = *(const u16x8*)(u2col + g * 16 + 8);
    const float bsum = (tid < 8) ? (ldin(bW2, j0 + tid, m_) + ldin(bU2, j0 + tid, m_)) : 0.f;

    for (int t = 0; t <= TSTEPS; ++t) {
        const bool need1 = (t < TSTEPS), need2 = (t >= 1);
        // A1 prefetch (independent of exchange)
        float azv = 0.f, arv = 0.f, awk = 0.f;
        if (tid < 8 && need1) {
            const float* a1p = A1 + (size_t)t * NV3 + j0 + tid;
            azv = a1p[0]; arv = a1p[512]; awk = a1p[1024];
        }
        // ---- poll A: h1(t) and h2(t-2) ----
        {
            const unsigned int eg1 = (unsigned int)t;
            const unsigned int eg2 = (t >= 2) ? (unsigned int)t : 0u;
            u64* p1 = h1x + (size_t)(t & 1) * 512 + 2 * tid;
            u64* p2 = h2x + (size_t)((t + 1) & 1) * 512 + 2 * tid;
            u64 x0, x1, y0, y1;
            for (;;) {
                x0 = AL64(p1); x1 = AL64(p1 + 1);
                y0 = AL64(p2); y1 = AL64(p2 + 1);
                if (tagof(x0) == eg1 && tagof(x1) == eg1 &&
                    tagof(y0) == eg2 && tagof(y1) == eg2) break;
                __builtin_amdgcn_s_sleep(1);
            }
            h1c[2 * tid] = tagval(x0); h1c[2 * tid + 1] = tagval(x1);
            h2c[2 * tid] = tagval(y0); h2c[2 * tid + 1] = tagval(y1);
        }
        __syncthreads();                                            // S1
        // ---- r-critical matvecs: Ur1·h1, Wr2·h1, Ur2·h2 ----
        {
            float q1 = 0.f, q3 = 0.f, q6 = 0.f;
#pragma unroll
            for (int u = 0; u < 8; ++u) {
                const int k = g * 16 + u;
                const float x1 = h1c[k], x2 = h2c[k];
                q1 = fmaf(x1, bf2f(wreg[2 * 1][u]), q1);   // Ur1
                q3 = fmaf(x1, bf2f(wreg[2 * 3][u]), q3);   // Wr2
                q6 = fmaf(x2, bf2f(wreg[2 * 6][u]), q6);   // Ur2
            }
#pragma unroll
            for (int u = 0; u < 8; ++u) {
                const int k = g * 16 + 8 + u;
                const float x1 = h1c[k], x2 = h2c[k];
                q1 = fmaf(x1, bf2f(wreg[2 * 1 + 1][u]), q1);
                q3 = fmaf(x1, bf2f(wreg[2 * 3 + 1][u]), q3);
                q6 = fmaf(x2, bf2f(wreg[2 * 6 + 1][u]), q6);
            }
            q1 += __shfl_xor(q1, 8); q1 += __shfl_xor(q1, 16); q1 += __shfl_xor(q1, 32);
            q3 += __shfl_xor(q3, 8); q3 += __shfl_xor(q3, 16); q3 += __shfl_xor(q3, 32);
            q6 += __shfl_xor(q6, 8); q6 += __shfl_xor(q6, 16); q6 += __shfl_xor(q6, 32);
            if (lane < 8) {
                red[wave][0][lane] = q1;
                red[wave][1][lane] = q3;
                red[wave][2][lane] = q6;
            }
        }
        __syncthreads();                                            // S2
        if (tid < 8) {   // early r store — starts the r round ASAP
            float s1 = red[0][0][tid] + red[1][0][tid] + red[2][0][tid] + red[3][0][tid];
            float s3 = red[0][1][tid] + red[1][1][tid] + red[2][1][tid] + red[3][1][tid];
            float s6 = red[0][2][tid] + red[1][2][tid] + red[2][2][tid] + red[3][2][tid];
            int j = j0 + tid;
            if (need1) AS64(&r1x[j], packtag(sigmoidf_(arv + s1), (unsigned int)t));
            if (need2) AS64(&r2x[j], packtag(sigmoidf_(s3 + s6), (unsigned int)t));
        }
        // ---- z/W matvecs (overlap the r round): Uz1, Wz2, W2, Uz2 ----
        {
            float q0 = 0.f, q2 = 0.f, q4 = 0.f, q5 = 0.f;
#pragma unroll
            for (int u = 0; u < 8; ++u) {
                const int k = g * 16 + u;
                const float x1 = h1c[k], x2 = h2c[k];
                q0 = fmaf(x1, bf2f(wreg[2 * 0][u]), q0);   // Uz1
                q2 = fmaf(x1, bf2f(wreg[2 * 2][u]), q2);   // Wz2
                q4 = fmaf(x1, bf2f(wreg[2 * 4][u]), q4);   // W2
                q5 = fmaf(x2, bf2f(wreg[2 * 5][u]), q5);   // Uz2
            }
#pragma unroll
            for (int u = 0; u < 8; ++u) {
                const int k = g * 16 + 8 + u;
                const float x1 = h1c[k], x2 = h2c[k];
                q0 = fmaf(x1, bf2f(wreg[2 * 0 + 1][u]), q0);
                q2 = fmaf(x1, bf2f(wreg[2 * 2 + 1][u]), q2);
                q4 = fmaf(x1, bf2f(wreg[2 * 4 + 1][u]), q4);
                q5 = fmaf(x2, bf2f(wreg[2 * 5 + 1][u]), q5);
            }
            q0 += __shfl_xor(q0, 8); q0 += __shfl_xor(q0, 16); q0 += __shfl_xor(q0, 32);
            q2 += __shfl_xor(q2, 8); q2 += __shfl_xor(q2, 16); q2 += __shfl_xor(q2, 32);
            q4 += __shfl_xor(q4, 8); q4 += __shfl_xor(q4, 16); q4 += __shfl_xor(q4, 32);
            q5 += __shfl_xor(q5, 8); q5 += __shfl_xor(q5, 16); q5 += __shfl_xor(q5, 32);
            if (lane < 8) {
                red[wave][3][lane] = q0;
                red[wave][4][lane] = q2;
                red[wave][5][lane] = q4;
                red[wave][6][lane] = q5;
            }
        }
        // ---- poll B: r1(t), r2(t) ----
        {
            u64 a0 = 0, a1 = 0, b0 = 0, b1 = 0;
            u64* q1p = r1x + 2 * tid;
            u64* q2p = r2x + 2 * tid;
            const unsigned int er = (unsigned int)t;
            for (;;) {
                if (need1) { a0 = AL64(q1p); a1 = AL64(q1p + 1); }
                if (need2) { b0 = AL64(q2p); b1 = AL64(q2p + 1); }
                bool ok = true;
                if (need1) ok = ok && (tagof(a0) == er) && (tagof(a1) == er);
                if (need2) ok = ok && (tagof(b0) == er) && (tagof(b1) == er);
                if (ok) break;
                __builtin_amdgcn_s_sleep(1);
            }
            if (need1) { r1c[2 * tid] = tagval(a0); r1c[2 * tid + 1] = tagval(a1); }
            if (need2) { r2c[2 * tid] = tagval(b0); r2c[2 * tid + 1] = tagval(b1); }
        }
        __syncthreads();                                            // S3
        // ---- merged U1/U2 matvec ----
        {
            float pa = 0.f, pb = 0.f;
#pragma unroll
            for (int u = 0; u < 8; ++u) {
                const int k = g * 16 + u;
                pa = fmaf(r1c[k] * h1c[k], bf2f(u1w0[u]), pa);
                pb = fmaf(r2c[k] * h2c[k], bf2f(u2w0[u]), pb);
            }
#pragma unroll
            for (int u = 0; u < 8; ++u) {
                const int k = g * 16 + 8 + u;
                pa = fmaf(r1c[k] * h1c[k], bf2f(u1w1[u]), pa);
                pb = fmaf(r2c[k] * h2c[k], bf2f(u2w1[u]), pb);
            }
            pa += __shfl_xor(pa, 8); pa += __shfl_xor(pa, 16); pa += __shfl_xor(pa, 32);
            pb += __shfl_xor(pb, 8); pb += __shfl_xor(pb, 16); pb += __shfl_xor(pb, 32);
            if (lane < 8) {
                red[wave][0][lane] = pa;   // slots 0/1 already consumed pre-S3
                red[wave][1][lane] = pb;
            }
        }
        __syncthreads();                                            // S4
        if (tid < 8) {   // finalize both layers
            float spa = red[0][0][tid] + red[1][0][tid] + red[2][0][tid] + red[3][0][tid];
            float spb = red[0][1][tid] + red[1][1][tid] + red[2][1][tid] + red[3][1][tid];
            float s0  = red[0][3][tid] + red[1][3][tid] + red[2][3][tid] + red[3][3][tid];
            float s2  = red[0][4][tid] + red[1][4][tid] + red[2][4][tid] + red[3][4][tid];
            float s4  = red[0][5][tid] + red[1][5][tid] + red[2][5][tid] + red[3][5][tid];
            float s5  = red[0][6][tid] + red[1][6][tid] + red[2][6][tid] + red[3][6][tid];
            int j = j0 + tid;
            if (need1) {
                float z1 = sigmoidf_(azv + s0);
                float ht1 = tanhf(awk + spa);
                float g1n = z1 * ht1 + (1.f - z1) * h1c[j];
                if (nanf_(g1n)) { atomicOr(flags, 4); g1n = 0.f; }
                AS64(&h1x[(size_t)((t + 1) & 1) * 512 + j], packtag(g1n, (unsigned int)(t + 1)));
            }
            if (need2) {
                float z2 = sigmoidf_(s2 + s5);
                float ht2 = tanhf(s4 + bsum + spb);
                float g2n = z2 * ht2 + (1.f - z2) * h2c[j];
                if (nanf_(g2n)) { atomicOr(flags, 4); g2n = 0.f; }
                AS64(&h2x[(size_t)(t & 1) * 512 + j], packtag(g2n, (unsigned int)(t + 1)));
                H2[(size_t)(t - 1) * 512 + j] = f2bf(g2n);
            }
        }
        __syncthreads();                                            // S5
    }
}

// ---------------------------------------------------------------------------
// MFMA GEMM #2 (fast path): logits = H2 @ WgT^T + bg, B pre-transposed bf16.
// ---------------------------------------------------------------------------
__global__ __launch_bounds__(256) void gemm_logits_fast(
    const u16* __restrict__ H2, const u16* __restrict__ WgT,
    const void* __restrict__ bg, void* __restrict__ out,
    float* __restrict__ rowsum, const int* __restrict__ modep, int* __restrict__ flags) {
    const int m = *modep;
    const int K = DIM;
    int tid = threadIdx.x, wave = tid >> 6, lane = tid & 63;
    int mw = wave & 1, nw = wave >> 1, l15 = lane & 15, q = lane >> 4;
    int mbase = blockIdx.y * 64 + mw * 32;
    int nbase = blockIdx.x * 128 + nw * 64;
    f32x4 acc[2][4];
#pragma unroll
    for (int mi = 0; mi < 2; ++mi)
#pragma unroll
        for (int ni = 0; ni < 4; ++ni) acc[mi][ni] = (f32x4){0.f, 0.f, 0.f, 0.f};
    for (int k0 = 0; k0 < K; k0 += 32) {
        s16x8 a[2], b[4];
#pragma unroll
        for (int mi = 0; mi < 2; ++mi)
            a[mi] = *(const s16x8*)(H2 + (size_t)(mbase + mi * 16 + l15) * K + k0 + q * 8);
#pragma unroll
        for (int ni = 0; ni < 4; ++ni) {
            int n = nbase + ni * 16 + l15;
            if (n >= VOC) n = VOC - 1;
            b[ni] = *(const s16x8*)(WgT + (size_t)n * 512 + k0 + q * 8);
        }
#pragma unroll
        for (int mi = 0; mi < 2; ++mi)
#pragma unroll
            for (int ni = 0; ni < 4; ++ni)
                acc[mi][ni] = __builtin_amdgcn_mfma_f32_16x16x32_bf16(a[mi], b[ni], acc[mi][ni], 0, 0, 0);
    }
    __shared__ float lds_rows[64];
    if (tid < 64) lds_rows[tid] = 0.f;
    __syncthreads();
#pragma unroll
    for (int mi = 0; mi < 2; ++mi)
#pragma unroll
        for (int r = 0; r < 4; ++r) {
            int row = mbase + mi * 16 + q * 4 + r;
            float esum = 0.f;
#pragma unroll
            for (int ni = 0; ni < 4; ++ni) {
                int col = nbase + ni * 16 + l15;
                float v = acc[mi][ni][r];
                if (col < VOC) {
                    v += ldin(bg, col, m);
                    if (nanf_(v)) { atomicOr(flags, 8); v = 0.f; }
                    if (m) ((float*)out)[(size_t)row * VOC + col] = v;
                    else   ((u16*)out)[(size_t)row * VOC + col] = f2bf(v);
                    esum += __expf(v);
                }
            }
            esum += __shfl_xor(esum, 1); esum += __shfl_xor(esum, 2);
            esum += __shfl_xor(esum, 4); esum += __shfl_xor(esum, 8);
            if (l15 == 0) atomicAdd(&lds_rows[row - blockIdx.y * 64], esum);
        }
    __syncthreads();
    if (tid < 64) atomicAdd(&rowsum[blockIdx.y * 64 + tid], lds_rows[tid]);
}

// slow fallback (no workspace for WgT): column-strided on-the-fly convert.
__global__ __launch_bounds__(256) void gemm_logits_slow(
    const u16* __restrict__ H2, const void* __restrict__ Wg,
    const void* __restrict__ bg, void* __restrict__ out,
    float* __restrict__ rowsum, const int* __restrict__ modep, int* __restrict__ flags) {
    const int m = *modep;
    const int K = DIM;
    int tid = threadIdx.x, wave = tid >> 6, lane = tid & 63;
    int mw = wave & 1, nw = wave >> 1, l15 = lane & 15, q = lane >> 4;
    int mbase = blockIdx.y * 64 + mw * 32;
    int nbase = blockIdx.x * 128 + nw * 64;
    f32x4 acc[2][4];
#pragma unroll
    for (int mi = 0; mi < 2; ++mi)
#pragma unroll
        for (int ni = 0; ni < 4; ++ni) acc[mi][ni] = (f32x4){0.f, 0.f, 0.f, 0.f};
    for (int k0 = 0; k0 < K; k0 += 32) {
        s16x8 a[2], b[4];
#pragma unroll
        for (int mi = 0; mi < 2; ++mi)
            a[mi] = *(const s16x8*)(H2 + (size_t)(mbase + mi * 16 + l15) * K + k0 + q * 8);
#pragma unroll
        for (int ni = 0; ni < 4; ++ni) {
            int n = nbase + ni * 16 + l15;
            if (n >= VOC) n = VOC - 1;
            size_t kb = (size_t)(k0 + q * 8) * VOC + n;
#pragma unroll
            for (int j = 0; j < 8; ++j) b[ni][j] = (short)f2bf(ldin(Wg, kb + (size_t)j * VOC, m));
        }
#pragma unroll
        for (int mi = 0; mi < 2; ++mi)
#pragma unroll
            for (int ni = 0; ni < 4; ++ni)
                acc[mi][ni] = __builtin_amdgcn_mfma_f32_16x16x32_bf16(a[mi], b[ni], acc[mi][ni], 0, 0, 0);
    }
    __shared__ float lds_rows[64];
    if (tid < 64) lds_rows[tid] = 0.f;
    __syncthreads();
#pragma unroll
    for (int mi = 0; mi < 2; ++mi)
#pragma unroll
        for (int r = 0; r < 4; ++r) {
            int row = mbase + mi * 16 + q * 4 + r;
            float esum = 0.f;
#pragma unroll
            for (int ni = 0; ni < 4; ++ni) {
                int col = nbase + ni * 16 + l15;
                float v = acc[mi][ni][r];
                if (col < VOC) {
                    v += ldin(bg, col, m);
                    if (nanf_(v)) { atomicOr(flags, 8); v = 0.f; }
                    if (m) ((float*)out)[(size_t)row * VOC + col] = v;
                    else   ((u16*)out)[(size_t)row * VOC + col] = f2bf(v);
                    esum += __expf(v);
                }
            }
            esum += __shfl_xor(esum, 1); esum += __shfl_xor(esum, 2);
            esum += __shfl_xor(esum, 4); esum += __shfl_xor(esum, 8);
            if (l15 == 0) atomicAdd(&lds_rows[row - blockIdx.y * 64], esum);
        }
    __syncthreads();
    if (tid < 64) atomicAdd(&rowsum[blockIdx.y * 64 + tid], lds_rows[tid]);
}

// ---------------------------------------------------------------------------
// in-place: out = logit - log(rowsum[row]); out[0] += 1000*stage if NaN seen.
// ---------------------------------------------------------------------------
__global__ __launch_bounds__(256) void logsoftmax_fix(void* __restrict__ out,
                                                      const float* __restrict__ rowsum,
                                                      const int* __restrict__ modep,
                                                      int* __restrict__ flags) {
    const int m = *modep;
    int row = blockIdx.y;
    int c0 = blockIdx.x * 2048 + threadIdx.x * 8;
    if (c0 >= VOC) return;
    float rs = rowsum[row];
    float ls = logf(rs);
    if (nanf_(ls) || !(rs > 0.f)) { atomicOr(flags, 16); ls = 0.f; }
    float sentinel = 0.f;
    if (row == 0 && c0 == 0) {
        int f = *flags;
        if (f) sentinel = 1000.f * (float)__ffs(f);
    }
    size_t base = (size_t)row * VOC + c0;
    if (m) {
        float* o = (float*)out;
        int lim = (c0 + 8 <= VOC) ? 8 : (VOC - c0);
        for (int i = 0; i < lim; ++i) {
            float v = o[base + i] - ls;
            if (i == 0) v += sentinel;
            o[base + i] = v;
        }
    } else {
        u16* o = (u16*)out;
        int lim = (c0 + 8 <= VOC) ? 8 : (VOC - c0);
        for (int i = 0; i < lim; ++i) {
            float v = bf2f(o[base + i]) - ls;
            if (i == 0) v += sentinel;
            o[base + i] = f2bf(v);
        }
    }
}

// ---------------------------------------------------------------------------
extern "C" void kernel_launch(void* const* d_in, const int* in_sizes, int n_in,
                              void* d_out, int out_size, void* d_ws, size_t ws_size,
                              hipStream_t stream) {
    const int* xidx = (const int*)d_in[0];
    const int* eidx = (const int*)d_in[1];
    const void* X    = d_in[2];
    const void* Wgat = d_in[3];
    const void* asrc = d_in[4];
    const void* adst = d_in[5];
    const void* bgat = d_in[6];
    const void* Wz1  = d_in[7];
    const void* Uz1  = d_in[8];
    const void* Wr1  = d_in[9];
    const void* Ur1  = d_in[10];
    const void* W1   = d_in[11];
    const void* bW1  = d_in[12];
    const void* U1   = d_in[13];
    const void* bU1  = d_in[14];
    const void* Wz2  = d_in[15];
    const void* Uz2  = d_in[16];
    const void* Wr2  = d_in[17];
    const void* Ur2  = d_in[18];
    const void* W2   = d_in[19];
    const void* bW2  = d_in[20];
    const void* U2   = d_in[21];
    const void* bU2  = d_in[22];
    const void* Wg   = d_in[23];
    const void* bg   = d_in[24];

    char* ws = (char*)d_ws;
    int*   modep  = (int*)(ws + OFF_MODE);
    int*   flags  = (int*)(ws + OFF_FLAGS);
    float* rowsum = (float*)(ws + OFF_ROWSUM);
    u64*   h1x    = (u64*)(ws + OFF_G1);
    u64*   h2x    = (u64*)(ws + OFF_G2);
    u64*   r1x    = (u64*)(ws + OFF_R1);
    u64*   r2x    = (u64*)(ws + OFF_R2);
    float* WAs    = (float*)(ws + OFF_WAS);
    float* WAd    = (float*)(ws + OFF_WAD);
    u16*   inp    = (u16*)(ws + OFF_INP);
    float* A1     = (float*)(ws + OFF_A1);
    u16*   H2     = (u16*)(ws + OFF_H2);
    u16*   wsT    = (u16*)(ws + OFF_WST);
    u16*   WcatT  = (u16*)(ws + OFF_WCATT);
    u16*   WgT    = (u16*)(ws + OFF_WGT);

    const bool big = ws_size >= WS_NEED_BIG;

    (void)hipMemsetAsync(ws, 0, ZERO_BYTES, stream);

    detect_mode<<<1, 64, 0, stream>>>(X, modep);

    prep_att<<<32, 256, 0, stream>>>(Wgat, asrc, adst, WAs, WAd, modep);

    Ptrs9 p9; // order: Uz1,Ur1,Wz2,Wr2,W2,Uz2,Ur2,U1,U2
    p9.p[0] = Uz1; p9.p[1] = Ur1; p9.p[2] = Wz2; p9.p[3] = Wr2; p9.p[4] = W2;
    p9.p[5] = Uz2; p9.p[6] = Ur2; p9.p[7] = U1;  p9.p[8] = U2;
    transpose9<<<dim3(16, 16, 9), 256, 0, stream>>>(p9, wsT, modep);

    Ptrs3 p3; p3.p[0] = Wz1; p3.p[1] = Wr1; p3.p[2] = W1;
    transpose3<<<dim3(16, 32, 3), 256, 0, stream>>>(p3, WcatT, modep);

    if (big)
        transpose_wg<<<dim3((VOC + 31) / 32, 16), 256, 0, stream>>>(Wg, WgT, modep);

    gat_kernel<<<S_SEQ, 256, 0, stream>>>(xidx, eidx, X, Wgat, WAs, WAd, bgat, inp, modep, flags);

    gemm_a1<<<dim3(NV3 / 128, S_SEQ / 64), 256, 0, stream>>>(inp, WcatT, bW1, bU1, A1, modep, flags);

    scan_kernel<<<KWG, 256, 0, stream>>>(A1, wsT, bW2, bU2, h1x, h2x, r1x, r2x, H2, modep, flags);

    if (big)
        gemm_logits_fast<<<dim3((VOC + 127) / 128, S_SEQ / 64), 256, 0, stream>>>(H2, WgT, bg, d_out, rowsum, modep, flags);
    else
        gemm_logits_slow<<<dim3((VOC + 127) / 128, S_SEQ / 64), 256, 0, stream>>>(H2, Wg, bg, d_out, rowsum, modep, flags);

    logsoftmax_fix<<<dim3(25, S_SEQ), 256, 0, stream>>>(d_out, rowsum, modep, flags);
}